// Round 2
// baseline (543.540 us; speedup 1.0000x reference)
//
#include <hip/hip_runtime.h>

typedef unsigned short u16;
typedef __bf16 bf8v __attribute__((ext_vector_type(8)));
typedef float f4v __attribute__((ext_vector_type(4)));
typedef f4v __attribute__((may_alias)) f4va;   // defeat TBAA for LDS/global reinterprets
typedef unsigned int u2v __attribute__((ext_vector_type(2)));
typedef u2v __attribute__((may_alias)) u2va;   // 8B packed bf16x4 stores

#define NTOK   49
#define NPAD   64
#define CDIM   96
#define FEAT_  56
#define HWIM   3136
#define SHIFT_ 3

// workspace layout (u16 units)
#define WIN_ELEMS (128 * 64 * 49 * 96)          // 38,535,168 u16 = 77.07 MB
#define QW_ELEMS  (288 * 96)                    // 27,648
#define PW_ELEMS  (96 * 96)                     // 9,216
#define WS_NEEDED ((size_t)(WIN_ELEMS + QW_ELEMS + PW_ELEMS) * 2)

__device__ __forceinline__ float b2f(u16 u) {
  unsigned v = ((unsigned)u) << 16;
  return __builtin_bit_cast(float, v);
}
__device__ __forceinline__ u16 f2b(float f) {   // HW RNE cvt on gfx950
  return __builtin_bit_cast(u16, (__bf16)f);
}
__device__ __forceinline__ bf8v fragld(const u16* p) {
  return __builtin_bit_cast(bf8v, *(const f4va*)p);   // 16B b128 load
}
__device__ __forceinline__ bf8v cvt8(const float* p) {
  f4v a = *(const f4va*)p;
  f4v b = *(const f4va*)(p + 4);
  union { u16 u[8]; bf8v v; } r;
#pragma unroll
  for (int j = 0; j < 4; ++j) { r.u[j] = f2b(a[j]); r.u[4 + j] = f2b(b[j]); }
  return r.v;
}
__device__ __forceinline__ f4v mfma16(bf8v a, bf8v b, f4v c) {
  return __builtin_amdgcn_mfma_f32_16x16x32_bf16(a, b, c, 0, 0, 0);
}
__device__ __forceinline__ int reg3(int g) { return g < 49 ? 0 : (g < 53 ? 1 : 2); }

// ---- K0: weights fp32 -> bf16 (once per call) --------------------------------
__global__ __launch_bounds__(256)
void swin_wcvt(const float* __restrict__ qw, const float* __restrict__ pw,
               u16* __restrict__ qwb, u16* __restrict__ pwb) {
  int i = blockIdx.x * 256 + threadIdx.x;        // 36864 threads exactly
  if (i < QW_ELEMS) qwb[i] = f2b(qw[i]);
  else              pwb[i - QW_ELEMS] = f2b(pw[i - QW_ELEMS]);
}

// ---- K1: LN + shift + window-partition + bf16 pack. block=(b,hs) -------------
// LDS 25.9 KB -> 6 blocks/CU (was 37.5 -> 4); 2 barriers (was 3); winbuf written
// directly as 3x b128 packed bf16 per lane (no wtile staging phase).
__global__ __launch_bounds__(256, 6)
void swin_ln_pack(const float* __restrict__ x,
                  const float* __restrict__ lng, const float* __restrict__ lnb,
                  u16* __restrict__ winbuf) {
  __shared__ __align__(16) float xf[CDIM][60];   // SOURCE row values
  __shared__ float ps[4][64], pq[4][64];
  __shared__ float gw[CDIM], bw[CDIM];

  const int bid = blockIdx.x;
  const int b = bid / FEAT_, hs = bid - b * FEAT_;   // shifted row
  int h = hs + SHIFT_; if (h >= FEAT_) h -= FEAT_;   // source row
  const int tid = threadIdx.x, wv = tid >> 6, lane = tid & 63;

  for (int i = tid; i < CDIM; i += 256) { gw[i] = lng[i]; bw[i] = lnb[i]; }

  // phase A: all-64-lane float4 loads of the SOURCE row (96 ch x 14 chunks)
  const float* base = x + (size_t)b * CDIM * HWIM + h * FEAT_;
  for (int idx = tid; idx < 1344; idx += 256) {
    int c = idx / 14, p4 = idx - c * 14;
    *(f4va*)&xf[c][p4 * 4] = *(const f4va*)(base + (size_t)c * HWIM + p4 * 4);
  }
  __syncthreads();

  // phase B1: LN partial sums per OUTPUT position ws (per-lane order unchanged)
  const int ws = lane;
  int wsrc = ws + SHIFT_; if (wsrc >= FEAT_) wsrc -= FEAT_;
  float s = 0.f, q = 0.f;
  if (ws < FEAT_)
    for (int i = 0; i < 24; ++i) {                   // wave owns channel quarter
      float v = xf[wv * 24 + i][wsrc];
      s += v; q += v * v;
    }
  ps[wv][lane] = s; pq[wv][lane] = q;
  __syncthreads();

  // phase B2: apply LN, pack 24 bf16, write winbuf directly (3x b128 per lane)
  if (ws < FEAT_) {
    float ts = ps[0][ws] + ps[1][ws] + ps[2][ws] + ps[3][ws];
    float tq = pq[0][ws] + pq[1][ws] + pq[2][ws] + pq[3][ws];
    float m = ts * (1.f / 96.f);
    float r = rsqrtf(tq * (1.f / 96.f) - m * m + 1e-5f);
    const int ww = ws / 7, wl = ws - ww * 7;
    const int wrow = hs / 7, tr = hs - wrow * 7;
    u16* dst = winbuf + ((size_t)((b * 64 + wrow * 8 + ww) * 49 + tr * 7 + wl)) * CDIM + wv * 24;
    union { u16 u[24]; f4v d[3]; } pk;
#pragma unroll
    for (int i = 0; i < 24; ++i) {
      int c = wv * 24 + i;
      pk.u[i] = f2b((xf[c][wsrc] - m) * r * gw[c] + bw[c]);
    }
#pragma unroll
    for (int j = 0; j < 3; ++j) *(f4va*)(dst + j * 8) = pk.d[j];
  }
}

// ---- K2: fused window attention (QKV -> attn -> proj), in-place on winbuf ----
// All MFMA epilogues use TRANSPOSED output (swap mfma operands -> lane holds 4
// consecutive COLUMNS of one row) so every result store is one packed
// ds_write_b64 instead of 4 conflicting ds_write_b16. v-tiles keep the original
// orientation (4 consecutive tokens at fixed d -> b64 into vt).
// Softmax is transposed too: lane owns one token-row m = wv*16+l15 with all 64
// j-scores in {quad}x{jt,rg} -> 15 in-reg ops + 2 shuffles (was 16 shuffles).
__global__ __launch_bounds__(256, 3)
void swin_attn(u16* __restrict__ winbuf,
               const u16* __restrict__ qwb, const u16* __restrict__ pwb,
               const float* __restrict__ qbv, const float* __restrict__ pbv,
               const float* __restrict__ rel) {
  __shared__ __align__(16) u16 qk[NPAD][200];  // {tokens, q|k, att, proj-out}
  __shared__ __align__(16) u16 vt[3][32][72];  // V^T per head [head][d][token]
  __shared__ __align__(16) u16 Pl[NPAD][72];   // probs (wave-private rows)
  __shared__ float rel_f[507];
  __shared__ __align__(16) float pb_f[CDIM];
  __shared__ __align__(16) float qb_f[3 * CDIM];

  const int blk = blockIdx.x;
  const int wi = blk & 63;
  const int whb = wi >> 3, wwb = wi & 7;
  const int tid = threadIdx.x;
  const int wv = tid >> 6, lane = tid & 63;
  const int quad = lane >> 4, l15 = lane & 15;

  u16* wbase = winbuf + (size_t)blk * (NTOK * CDIM);

  // ---- phase 1: contiguous coop load (9408 B) + zero pad rows + params -------
  for (int idx = tid; idx < 588; idx += 256) {
    int row = idx / 12, cc = idx - row * 12;
    *(f4va*)&qk[row][cc * 8] = *(const f4va*)(wbase + idx * 8);
  }
  {
    f4v z = {0.f, 0.f, 0.f, 0.f};
    for (int idx = tid; idx < 180; idx += 256) {    // rows 49..63, cols 0..95
      int row = 49 + idx / 12, cc = idx - (idx / 12) * 12;
      *(f4va*)&qk[row][cc * 8] = z;
    }
  }
  for (int i = tid; i < 507; i += 256) rel_f[i] = rel[i];
  for (int i = tid; i < 3 * CDIM; i += 256) qb_f[i] = qbv[i];
  for (int i = tid; i < CDIM; i += 256) pb_f[i] = pbv[i];
  __syncthreads();

  // ---- phase 3: QKV GEMM (64x96)@(96x288), N-split across waves --------------
  {
    bf8v a[4][3];
    for (int mt = 0; mt < 4; ++mt)
      for (int kt = 0; kt < 3; ++kt)
        a[mt][kt] = fragld(&qk[mt * 16 + l15][kt * 32 + quad * 8]);
    __syncthreads();   // all waves hold A-frags; q-writes may now clobber input
    const float qscale = 0.17677669529663687f;      // 1/sqrt(32)
    for (int nt = wv; nt < 18; nt += 4) {
      int n = nt * 16 + l15;
      bf8v bf[3];
      for (int kt = 0; kt < 3; ++kt)
        bf[kt] = fragld(qwb + n * CDIM + kt * 32 + quad * 8);
      if (nt < 12) {
        // q/k: transposed output -> lane holds C[n0+rg][m], b64 row-stores
        const int n0 = nt * 16 + quad * 4;
        f4v bias = *(const f4va*)&qb_f[n0];
        const bool isq = (nt < 6);
        for (int mt = 0; mt < 4; ++mt) {
          f4v c = {0.f, 0.f, 0.f, 0.f};
          c = mfma16(bf[0], a[mt][0], c);
          c = mfma16(bf[1], a[mt][1], c);
          c = mfma16(bf[2], a[mt][2], c);
          union { u16 u[4]; u2v d; } pk;
#pragma unroll
          for (int rg = 0; rg < 4; ++rg) {
            float v = c[rg] + bias[rg];
            if (isq) v *= qscale;
            pk.u[rg] = f2b(v);
          }
          *(u2va*)&qk[mt * 16 + l15][n0] = pk.d;
        }
      } else {
        // v: original orientation -> lane holds C[m0+rg][n], b64 into vt cols
        float bias = qb_f[n];
        const int hd = (n - 192) >> 5, dc = (n - 192) & 31;
        for (int mt = 0; mt < 4; ++mt) {
          f4v c = {0.f, 0.f, 0.f, 0.f};
          c = mfma16(a[mt][0], bf[0], c);
          c = mfma16(a[mt][1], bf[1], c);
          c = mfma16(a[mt][2], bf[2], c);
          union { u16 u[4]; u2v d; } pk;
#pragma unroll
          for (int rg = 0; rg < 4; ++rg) pk.u[rg] = f2b(c[rg] + bias);
          *(u2va*)&vt[hd][dc][mt * 16 + quad * 4] = pk.d;
        }
      }
    }
  }
  __syncthreads();

  // ---- phase 4: attention per head; lane owns token-row m = wv*16+l15 --------
  {
    const int mrow = wv * 16 + l15;
    int mc = mrow > 48 ? 48 : mrow;
    const int ri = mc / 7, ci = mc - ri * 7;
    const int rcnt = reg3(whb * 7 + ri) * 3 + reg3(wwb * 7 + ci);
    // hoist h-invariant j-side quantities (j = jt*16 + quad*4 + rg)
    int ib_[4][4]; float ms_[4][4]; bool jv_[4][4];
    for (int jt = 0; jt < 4; ++jt)
      for (int rg = 0; rg < 4; ++rg) {
        int j = jt * 16 + quad * 4 + rg;
        jv_[jt][rg] = (j < NTOK);
        int jj = j > 48 ? 48 : j;
        int rj = jj / 7, cj = jj - rj * 7;
        int jcnt = reg3(whb * 7 + rj) * 3 + reg3(wwb * 7 + cj);
        ib_[jt][rg] = ((ri - rj + 6) * 13 + (ci - cj + 6)) * 3;
        ms_[jt][rg] = (jcnt != rcnt) ? -100.f : 0.f;
      }
    for (int h = 0; h < 3; ++h) {
      bf8v aq = fragld(&qk[wv * 16 + l15][h * 32 + quad * 8]);   // B operand (col=m)
      f4v S[4];
      for (int jt = 0; jt < 4; ++jt) {
        bf8v bk = fragld(&qk[jt * 16 + l15][96 + h * 32 + quad * 8]);  // A (row=j)
        f4v z = {0.f, 0.f, 0.f, 0.f};
        S[jt] = mfma16(bk, aq, z);     // S'[j][m]
      }
      for (int jt = 0; jt < 4; ++jt)
#pragma unroll
        for (int rg = 0; rg < 4; ++rg) {
          if (jv_[jt][rg]) S[jt][rg] += rel_f[ib_[jt][rg] + h] + ms_[jt][rg];
          else             S[jt][rg] = -1e30f;
        }
      // softmax over j for this lane's row m: 16 in-reg + cross-quad (2 shfl)
      float mx0 = fmaxf(fmaxf(S[0][0], S[0][1]), fmaxf(S[0][2], S[0][3]));
      float mx1 = fmaxf(fmaxf(S[1][0], S[1][1]), fmaxf(S[1][2], S[1][3]));
      float mx2 = fmaxf(fmaxf(S[2][0], S[2][1]), fmaxf(S[2][2], S[2][3]));
      float mx3 = fmaxf(fmaxf(S[3][0], S[3][1]), fmaxf(S[3][2], S[3][3]));
      float mx = fmaxf(fmaxf(mx0, mx1), fmaxf(mx2, mx3));
      mx = fmaxf(mx, __shfl_xor(mx, 16, 64));
      mx = fmaxf(mx, __shfl_xor(mx, 32, 64));
      float s = 0.f;
      for (int jt = 0; jt < 4; ++jt) {
        float e0 = __expf(S[jt][0] - mx), e1 = __expf(S[jt][1] - mx);
        float e2 = __expf(S[jt][2] - mx), e3 = __expf(S[jt][3] - mx);
        S[jt][0] = e0; S[jt][1] = e1; S[jt][2] = e2; S[jt][3] = e3;
        s += (e0 + e1) + (e2 + e3);
      }
      s += __shfl_xor(s, 16, 64);
      s += __shfl_xor(s, 32, 64);
      float inv = 1.f / s;
      for (int jt = 0; jt < 4; ++jt) {
        union { u16 u[4]; u2v d; } pk;
#pragma unroll
        for (int rg = 0; rg < 4; ++rg) pk.u[rg] = f2b(S[jt][rg] * inv);
        *(u2va*)&Pl[mrow][jt * 16 + quad * 4] = pk.d;
      }
      bf8v ap0 = fragld(&Pl[wv * 16 + l15][quad * 8]);        // B operand (col=m)
      bf8v ap1 = fragld(&Pl[wv * 16 + l15][32 + quad * 8]);
      for (int dt = 0; dt < 2; ++dt) {
        bf8v bv0 = fragld(&vt[h][dt * 16 + l15][quad * 8]);   // A operand (row=d)
        bf8v bv1 = fragld(&vt[h][dt * 16 + l15][32 + quad * 8]);
        f4v c = {0.f, 0.f, 0.f, 0.f};
        c = mfma16(bv0, ap0, c);
        c = mfma16(bv1, ap1, c);     // C'[d][m]
        // att aliases q-region cols 32h..32h+31, own-wave rows only
        union { u16 u[4]; u2v d; } pk;
#pragma unroll
        for (int rg = 0; rg < 4; ++rg) pk.u[rg] = f2b(c[rg]);
        *(u2va*)&qk[mrow][h * 32 + dt * 16 + quad * 4] = pk.d;
      }
    }
  }
  __syncthreads();

  // ---- phase 5: proj GEMM (64x96)@(96x96) -> qk cols 0..95 (in-place) --------
  // balanced: 24 (nt,mt) units, 6 per wave; transposed output, b64 stores
  {
    bf8v a[4][3];
    for (int mt = 0; mt < 4; ++mt)
      for (int kt = 0; kt < 3; ++kt)
        a[mt][kt] = fragld(&qk[mt * 16 + l15][kt * 32 + quad * 8]);
    __syncthreads();   // all waves hold att A-frags; out-writes may now clobber
    int lastnt = -1;
    bf8v bf[3]; f4v bias = {0.f, 0.f, 0.f, 0.f};
    for (int u = wv * 6; u < wv * 6 + 6; ++u) {
      int nt = u >> 2, mt = u & 3;
      if (nt != lastnt) {
        lastnt = nt;
        int n = nt * 16 + l15;
        for (int kt = 0; kt < 3; ++kt)
          bf[kt] = fragld(pwb + n * CDIM + kt * 32 + quad * 8);
        bias = *(const f4va*)&pb_f[nt * 16 + quad * 4];
      }
      f4v c = {0.f, 0.f, 0.f, 0.f};
      c = mfma16(bf[0], a[mt][0], c);
      c = mfma16(bf[1], a[mt][1], c);
      c = mfma16(bf[2], a[mt][2], c);
      union { u16 u[4]; u2v d; } pk;
#pragma unroll
      for (int rg = 0; rg < 4; ++rg) pk.u[rg] = f2b(c[rg] + bias[rg]);
      *(u2va*)&qk[mt * 16 + l15][nt * 16 + quad * 4] = pk.d;
    }
  }
  __syncthreads();

  // ---- phase 6: contiguous coop store (in-place over this block's window) ----
  for (int idx = tid; idx < 588; idx += 256) {
    int row = idx / 12, cc = idx - row * 12;
    *(f4va*)(wbase + idx * 8) = *(const f4va*)&qk[row][cc * 8];
  }
}

// ---- K3: window-reverse + unshift + bf16->fp32 transpose. block=(b,h) --------
// sigma row-permutation of wtile kills the 7-way scalar-read bank conflicts:
// storage row sig(w) = (w>>2)|((w&3)<<4); store loop reads rows p4+16j (2-way).
__global__ __launch_bounds__(256, 8)
void swin_unpack(const u16* __restrict__ winbuf, float* __restrict__ out) {
  __shared__ __align__(16) u16 wtile[64][104];   // [sig(w)][c]
  const int bid = blockIdx.x;
  const int b = bid / FEAT_, h = bid - b * FEAT_;
  int hs = h - SHIFT_; if (hs < 0) hs += FEAT_;
  const int wrow = hs / 7, tr = hs - wrow * 7;
  const int tid = threadIdx.x, wv = tid >> 6, lane = tid & 63;

  for (int idx = tid; idx < 672; idx += 256) {
    int ww = idx / 84, r = idx - ww * 84;
    const u16* src = winbuf + ((size_t)((b * 64 + wrow * 8 + ww) * 49 + tr * 7)) * CDIM + r * 8;
    int wl = r / 12, cc = r - wl * 12;
    int ws = ww * 7 + wl;
    int w = ws + SHIFT_; if (w >= FEAT_) w -= FEAT_;
    int sr = (w >> 2) | ((w & 3) << 4);
    *(f4va*)&wtile[sr][cc * 8] = *(const f4va*)src;
  }
  __syncthreads();
  // vectorized float4 stores along w: 4 channel-groups x 14 lanes
  if (lane < 56) {
    const int g = lane / 14, p4 = lane - g * 14;
    float* obase = out + (size_t)b * CDIM * HWIM + h * FEAT_ + p4 * 4;
    for (int i = 0; i < 6; ++i) {
      int c = wv * 24 + i * 4 + g;
      f4v v;
#pragma unroll
      for (int j = 0; j < 4; ++j) v[j] = b2f(wtile[p4 + 16 * j][c]);  // sig(4p4+j)
      *(f4va*)(obase + (size_t)c * HWIM) = v;
    }
  }
}

// ---- fallback: round-2 monolithic kernel (used if ws too small) --------------
__global__ __launch_bounds__(256, 2)
void swin_fused_fb(const float* __restrict__ x,
                   const float* __restrict__ lng, const float* __restrict__ lnb,
                   const float* __restrict__ qw,  const float* __restrict__ qbv,
                   const float* __restrict__ pw,  const float* __restrict__ pbv,
                   const float* __restrict__ rel,
                   float* __restrict__ out) {
  __shared__ union { float xf[NTOK][97]; u16 qk[NPAD][200]; } A;
  __shared__ union { u16 win16[NPAD][104]; u16 outb[NPAD][98]; } Bu;
  __shared__ u16 vt[3][32][72];
  __shared__ u16 Pl[NPAD][72];
  __shared__ u16 att[NPAD][104];
  __shared__ float gw[CDIM], bwt[CDIM];
  __shared__ float rel_f[507];
  __shared__ float pb_f[CDIM];
  __shared__ float qb_f[3 * CDIM];

  const int blk = blockIdx.x;
  const int b = blk >> 6, wi = blk & 63;
  const int whb = wi >> 3, wwb = wi & 7;
  const int tid = threadIdx.x, wv = tid >> 6, lane = tid & 63;
  const int quad = lane >> 4, l15 = lane & 15;
  {
    int p = lane;
    if (p < NTOK) {
      int r = p / 7, cw = p - r * 7;
      int h = whb * 7 + r + SHIFT_;  if (h >= FEAT_) h -= FEAT_;
      int w = wwb * 7 + cw + SHIFT_; if (w >= FEAT_) w -= FEAT_;
      const float* xp = x + b * CDIM * HWIM + h * FEAT_ + w;
      for (int c = wv; c < CDIM; c += 4) A.xf[p][c] = xp[c * HWIM];
    }
    for (int i = tid; i < CDIM; i += 256) { gw[i] = lng[i]; bwt[i] = lnb[i]; pb_f[i] = pbv[i]; }
    for (int i = tid; i < 507; i += 256) rel_f[i] = rel[i];
    for (int i = tid; i < 3 * CDIM; i += 256) qb_f[i] = qbv[i];
  }
  __syncthreads();
  {
    int p = wv * 16 + (lane >> 2), cg = lane & 3;
    float s = 0.f, q = 0.f;
    if (p < NTOK)
      for (int i = 0; i < 24; ++i) { float v = A.xf[p][cg * 24 + i]; s += v; q += v * v; }
    s += __shfl_xor(s, 1, 64); s += __shfl_xor(s, 2, 64);
    q += __shfl_xor(q, 1, 64); q += __shfl_xor(q, 2, 64);
    float m = s * (1.f / 96.f);
    float r = rsqrtf(q * (1.f / 96.f) - m * m + 1e-5f);
    for (int i = 0; i < 24; ++i) {
      int c = cg * 24 + i;
      float v = (p < NTOK) ? (A.xf[p][c] - m) * r * gw[c] + bwt[c] : 0.f;
      Bu.win16[p][c] = f2b(v);
    }
  }
  __syncthreads();
  {
    bf8v a[4][3];
    for (int mt = 0; mt < 4; ++mt)
      for (int kt = 0; kt < 3; ++kt)
        a[mt][kt] = fragld(&Bu.win16[mt * 16 + l15][kt * 32 + quad * 8]);
    const float qscale = 0.17677669529663687f;
    for (int nt = wv; nt < 18; nt += 4) {
      int n = nt * 16 + l15;
      const float* wr = qw + n * CDIM;
      bf8v bf[3];
      for (int kt = 0; kt < 3; ++kt) bf[kt] = cvt8(wr + kt * 32 + quad * 8);
      float bias = qb_f[n];
      for (int mt = 0; mt < 4; ++mt) {
        f4v c = {0.f, 0.f, 0.f, 0.f};
        c = mfma16(a[mt][0], bf[0], c);
        c = mfma16(a[mt][1], bf[1], c);
        c = mfma16(a[mt][2], bf[2], c);
        for (int rg = 0; rg < 4; ++rg) {
          int m = mt * 16 + quad * 4 + rg;
          float v = c[rg] + bias;
          if (n < 96)        A.qk[m][n] = f2b(v * qscale);
          else if (n < 192)  A.qk[m][n] = f2b(v);
          else               vt[(n - 192) >> 5][(n - 192) & 31][m] = f2b(v);
        }
      }
    }
  }
  __syncthreads();
  {
    const int rbase = wv * 16 + quad * 4;
    int rcnt[4], ri_[4], ci_[4];
    for (int rg = 0; rg < 4; ++rg) {
      int r = rbase + rg; if (r > 48) r = 48;
      int ri = r / 7, ci = r - ri * 7;
      ri_[rg] = ri; ci_[rg] = ci;
      rcnt[rg] = reg3(whb * 7 + ri) * 3 + reg3(wwb * 7 + ci);
    }
    for (int h = 0; h < 3; ++h) {
      bf8v aq = fragld(&A.qk[wv * 16 + l15][h * 32 + quad * 8]);
      f4v S[4];
      for (int nt = 0; nt < 4; ++nt) {
        bf8v bk = fragld(&A.qk[nt * 16 + l15][96 + h * 32 + quad * 8]);
        f4v z = {0.f, 0.f, 0.f, 0.f};
        S[nt] = mfma16(aq, bk, z);
      }
      for (int nt = 0; nt < 4; ++nt) {
        int j = nt * 16 + l15;
        if (j < NTOK) {
          int rj = j / 7, cj = j - rj * 7;
          int jcnt = reg3(whb * 7 + rj) * 3 + reg3(wwb * 7 + cj);
          for (int rg = 0; rg < 4; ++rg) {
            float add = rel_f[((ri_[rg] - rj + 6) * 13 + (ci_[rg] - cj + 6)) * 3 + h];
            if (jcnt != rcnt[rg]) add -= 100.f;
            S[nt][rg] += add;
          }
        } else {
          for (int rg = 0; rg < 4; ++rg) S[nt][rg] = -1e30f;
        }
      }
      float inv[4];
      for (int rg = 0; rg < 4; ++rg) {
        float m = fmaxf(fmaxf(S[0][rg], S[1][rg]), fmaxf(S[2][rg], S[3][rg]));
        for (int off = 1; off < 16; off <<= 1) m = fmaxf(m, __shfl_xor(m, off, 64));
        float s = 0.f;
        for (int nt = 0; nt < 4; ++nt) { float e = __expf(S[nt][rg] - m); S[nt][rg] = e; s += e; }
        for (int off = 1; off < 16; off <<= 1) s += __shfl_xor(s, off, 64);
        inv[rg] = 1.f / s;
      }
      for (int nt = 0; nt < 4; ++nt) {
        int j = nt * 16 + l15;
        for (int rg = 0; rg < 4; ++rg) Pl[rbase + rg][j] = f2b(S[nt][rg] * inv[rg]);
      }
      bf8v ap0 = fragld(&Pl[wv * 16 + l15][quad * 8]);
      bf8v ap1 = fragld(&Pl[wv * 16 + l15][32 + quad * 8]);
      for (int nt = 0; nt < 2; ++nt) {
        bf8v bv0 = fragld(&vt[h][nt * 16 + l15][quad * 8]);
        bf8v bv1 = fragld(&vt[h][nt * 16 + l15][32 + quad * 8]);
        f4v c = {0.f, 0.f, 0.f, 0.f};
        c = mfma16(ap0, bv0, c);
        c = mfma16(ap1, bv1, c);
        for (int rg = 0; rg < 4; ++rg)
          att[rbase + rg][h * 32 + nt * 16 + l15] = f2b(c[rg]);
      }
    }
  }
  __syncthreads();
  {
    bf8v a[4][3];
    for (int mt = 0; mt < 4; ++mt)
      for (int kt = 0; kt < 3; ++kt)
        a[mt][kt] = fragld(&att[mt * 16 + l15][kt * 32 + quad * 8]);
    for (int nt = wv; nt < 6; nt += 4) {
      int n = nt * 16 + l15;
      const float* wr = pw + n * CDIM;
      bf8v bf[3];
      for (int kt = 0; kt < 3; ++kt) bf[kt] = cvt8(wr + kt * 32 + quad * 8);
      float bias = pb_f[n];
      for (int mt = 0; mt < 4; ++mt) {
        f4v c = {0.f, 0.f, 0.f, 0.f};
        c = mfma16(a[mt][0], bf[0], c);
        c = mfma16(a[mt][1], bf[1], c);
        c = mfma16(a[mt][2], bf[2], c);
        for (int rg = 0; rg < 4; ++rg)
          Bu.outb[mt * 16 + quad * 4 + rg][n] = f2b(c[rg] + bias);
      }
    }
  }
  __syncthreads();
  {
    int p = lane;
    if (p < NTOK) {
      int r = p / 7, cw = p - r * 7;
      int h = whb * 7 + r + SHIFT_;  if (h >= FEAT_) h -= FEAT_;
      int w = wwb * 7 + cw + SHIFT_; if (w >= FEAT_) w -= FEAT_;
      float* op = out + b * CDIM * HWIM + h * FEAT_ + w;
      for (int c = wv; c < CDIM; c += 4) op[c * HWIM] = b2f(Bu.outb[p][c]);
    }
  }
}

extern "C" void kernel_launch(void* const* d_in, const int* in_sizes, int n_in,
                              void* d_out, int out_size, void* d_ws, size_t ws_size,
                              hipStream_t stream) {
  (void)in_sizes; (void)n_in; (void)out_size;
  const float* x   = (const float*)d_in[0];
  const float* lng = (const float*)d_in[1];
  const float* lnb = (const float*)d_in[2];
  const float* qw  = (const float*)d_in[3];
  const float* qbv = (const float*)d_in[4];
  const float* pw  = (const float*)d_in[5];
  const float* pbv = (const float*)d_in[6];
  const float* rel = (const float*)d_in[7];
  float* out = (float*)d_out;

  if (ws_size >= WS_NEEDED) {
    u16* winbuf = (u16*)d_ws;
    u16* qwb = winbuf + WIN_ELEMS;
    u16* pwb = qwb + QW_ELEMS;
    swin_wcvt<<<dim3(144), dim3(256), 0, stream>>>(qw, pw, qwb, pwb);
    swin_ln_pack<<<dim3(128 * FEAT_), dim3(256), 0, stream>>>(x, lng, lnb, winbuf);
    swin_attn<<<dim3(8192), dim3(256), 0, stream>>>(winbuf, qwb, pwb, qbv, pbv, rel);
    swin_unpack<<<dim3(128 * FEAT_), dim3(256), 0, stream>>>(winbuf, out);
  } else {
    swin_fused_fb<<<dim3(8192), dim3(256), 0, stream>>>(x, lng, lnb, qw, qbv, pw, pbv, rel, out);
  }
}

// Round 3
// 447.668 us; speedup vs baseline: 1.2142x; 1.2142x over previous
//
#include <hip/hip_runtime.h>

typedef unsigned short u16;
typedef __bf16 bf8v __attribute__((ext_vector_type(8)));
typedef float f4v __attribute__((ext_vector_type(4)));
typedef f4v __attribute__((may_alias)) f4va;   // defeat TBAA for LDS/global reinterprets
typedef unsigned int u2v __attribute__((ext_vector_type(2)));
typedef u2v __attribute__((may_alias)) u2va;   // 8B packed bf16x4 stores
typedef unsigned int u4v __attribute__((ext_vector_type(4)));
typedef u4v __attribute__((may_alias)) u4va;   // 16B packed bf16x8 stores

#define NTOK   49
#define NPAD   64
#define CDIM   96
#define FEAT_  56
#define HWIM   3136
#define SHIFT_ 3

// workspace layout (u16 units)
#define WIN_ELEMS (128 * 64 * 49 * 96)          // 38,535,168 u16 = 77.07 MB
#define QW_ELEMS  (288 * 96)                    // 27,648
#define PW_ELEMS  (96 * 96)                     // 9,216
#define WS_NEEDED ((size_t)(WIN_ELEMS + QW_ELEMS + PW_ELEMS) * 2)

__device__ __forceinline__ float b2f(u16 u) {
  unsigned v = ((unsigned)u) << 16;
  return __builtin_bit_cast(float, v);
}
__device__ __forceinline__ u16 f2b(float f) {   // HW RNE cvt on gfx950
  return __builtin_bit_cast(u16, (__bf16)f);
}
__device__ __forceinline__ unsigned pk2(float a, float b) {  // bf16x2 pack, pure ALU
  return (unsigned)f2b(a) | ((unsigned)f2b(b) << 16);
}
__device__ __forceinline__ bf8v fragld(const u16* p) {
  return __builtin_bit_cast(bf8v, *(const f4va*)p);   // 16B b128 load
}
__device__ __forceinline__ bf8v cvt8(const float* p) {
  f4v a = *(const f4va*)p;
  f4v b = *(const f4va*)(p + 4);
  union { u16 u[8]; bf8v v; } r;
#pragma unroll
  for (int j = 0; j < 4; ++j) { r.u[j] = f2b(a[j]); r.u[4 + j] = f2b(b[j]); }
  return r.v;
}
__device__ __forceinline__ f4v mfma16(bf8v a, bf8v b, f4v c) {
  return __builtin_amdgcn_mfma_f32_16x16x32_bf16(a, b, c, 0, 0, 0);
}
__device__ __forceinline__ int reg3(int g) { return g < 49 ? 0 : (g < 53 ? 1 : 2); }

// ---- K0: weights fp32 -> bf16 (once per call) --------------------------------
__global__ __launch_bounds__(256)
void swin_wcvt(const float* __restrict__ qw, const float* __restrict__ pw,
               u16* __restrict__ qwb, u16* __restrict__ pwb) {
  int i = blockIdx.x * 256 + threadIdx.x;        // 36864 threads exactly
  if (i < QW_ELEMS) qwb[i] = f2b(qw[i]);
  else              pwb[i - QW_ELEMS] = f2b(pw[i - QW_ELEMS]);
}

// ---- K1: LN + shift + window-partition + bf16 pack. block=(b,hs) -------------
// LDS 25.9 KB -> 6 blocks/CU; 2 barriers; winbuf written directly as 3x 16B
// packed-bf16 stores per lane (integer packing -- NO unions, rule #20 safe).
__global__ __launch_bounds__(256, 6)
void swin_ln_pack(const float* __restrict__ x,
                  const float* __restrict__ lng, const float* __restrict__ lnb,
                  u16* __restrict__ winbuf) {
  __shared__ __align__(16) float xf[CDIM][60];   // SOURCE row values
  __shared__ float ps[4][64], pq[4][64];
  __shared__ float gw[CDIM], bw[CDIM];

  const int bid = blockIdx.x;
  const int b = bid / FEAT_, hs = bid - b * FEAT_;   // shifted row
  int h = hs + SHIFT_; if (h >= FEAT_) h -= FEAT_;   // source row
  const int tid = threadIdx.x, wv = tid >> 6, lane = tid & 63;

  for (int i = tid; i < CDIM; i += 256) { gw[i] = lng[i]; bw[i] = lnb[i]; }

  // phase A: all-64-lane float4 loads of the SOURCE row (96 ch x 14 chunks)
  const float* base = x + (size_t)b * CDIM * HWIM + h * FEAT_;
  for (int idx = tid; idx < 1344; idx += 256) {
    int c = idx / 14, p4 = idx - c * 14;
    *(f4va*)&xf[c][p4 * 4] = *(const f4va*)(base + (size_t)c * HWIM + p4 * 4);
  }
  __syncthreads();

  // phase B1: LN partial sums per OUTPUT position ws (per-lane order unchanged)
  const int ws = lane;
  int wsrc = ws + SHIFT_; if (wsrc >= FEAT_) wsrc -= FEAT_;
  float s = 0.f, q = 0.f;
  if (ws < FEAT_)
    for (int i = 0; i < 24; ++i) {                   // wave owns channel quarter
      float v = xf[wv * 24 + i][wsrc];
      s += v; q += v * v;
    }
  ps[wv][lane] = s; pq[wv][lane] = q;
  __syncthreads();

  // phase B2: apply LN, pack 24 bf16 via integer packs, 3x 16B stores
  if (ws < FEAT_) {
    float ts = ps[0][ws] + ps[1][ws] + ps[2][ws] + ps[3][ws];
    float tq = pq[0][ws] + pq[1][ws] + pq[2][ws] + pq[3][ws];
    float m = ts * (1.f / 96.f);
    float r = rsqrtf(tq * (1.f / 96.f) - m * m + 1e-5f);
    const int ww = ws / 7, wl = ws - ww * 7;
    const int wrow = hs / 7, tr = hs - wrow * 7;
    u16* dst = winbuf + ((size_t)((b * 64 + wrow * 8 + ww) * 49 + tr * 7 + wl)) * CDIM + wv * 24;
    unsigned pkw[12];
#pragma unroll
    for (int i = 0; i < 12; ++i) {
      int c = wv * 24 + 2 * i;
      float v0 = (xf[c][wsrc] - m) * r * gw[c] + bw[c];
      float v1 = (xf[c + 1][wsrc] - m) * r * gw[c + 1] + bw[c + 1];
      pkw[i] = pk2(v0, v1);
    }
    u4v d0 = {pkw[0], pkw[1], pkw[2], pkw[3]};
    u4v d1 = {pkw[4], pkw[5], pkw[6], pkw[7]};
    u4v d2 = {pkw[8], pkw[9], pkw[10], pkw[11]};
    *(u4va*)(dst)      = d0;
    *(u4va*)(dst + 8)  = d1;
    *(u4va*)(dst + 16) = d2;
  }
}

// ---- K2: fused window attention (QKV -> attn -> proj), in-place on winbuf ----
// Transposed MFMA epilogues (swap operands -> lane holds 4 consecutive COLUMNS
// of one row) so every result store is one packed b64 (integer pk2, no unions).
// Softmax transposed: lane owns token-row m with all 64 j-scores in regs ->
// 15 in-reg ops + 2 shuffles. ALL register arrays statically indexed (rule #20).
__global__ __launch_bounds__(256, 3)
void swin_attn(u16* __restrict__ winbuf,
               const u16* __restrict__ qwb, const u16* __restrict__ pwb,
               const float* __restrict__ qbv, const float* __restrict__ pbv,
               const float* __restrict__ rel) {
  __shared__ __align__(16) u16 qk[NPAD][200];  // {tokens, q|k, att, proj-out}
  __shared__ __align__(16) u16 vt[3][32][72];  // V^T per head [head][d][token]
  __shared__ __align__(16) u16 Pl[NPAD][72];   // probs (wave-private rows)
  __shared__ float rel_f[507];
  __shared__ __align__(16) float pb_f[CDIM];
  __shared__ __align__(16) float qb_f[3 * CDIM];

  const int blk = blockIdx.x;
  const int wi = blk & 63;
  const int whb = wi >> 3, wwb = wi & 7;
  const int tid = threadIdx.x;
  const int wv = tid >> 6, lane = tid & 63;
  const int quad = lane >> 4, l15 = lane & 15;

  u16* wbase = winbuf + (size_t)blk * (NTOK * CDIM);

  // ---- phase 1: contiguous coop load (9408 B) + zero pad rows + params -------
  for (int idx = tid; idx < 588; idx += 256) {
    int row = idx / 12, cc = idx - row * 12;
    *(f4va*)&qk[row][cc * 8] = *(const f4va*)(wbase + idx * 8);
  }
  {
    f4v z = {0.f, 0.f, 0.f, 0.f};
    for (int idx = tid; idx < 180; idx += 256) {    // rows 49..63, cols 0..95
      int row = 49 + idx / 12, cc = idx - (idx / 12) * 12;
      *(f4va*)&qk[row][cc * 8] = z;
    }
  }
  for (int i = tid; i < 507; i += 256) rel_f[i] = rel[i];
  for (int i = tid; i < 3 * CDIM; i += 256) qb_f[i] = qbv[i];
  for (int i = tid; i < CDIM; i += 256) pb_f[i] = pbv[i];
  __syncthreads();

  // ---- phase 3: QKV GEMM (64x96)@(96x288), N-split across waves --------------
  {
    bf8v a[4][3];
#pragma unroll
    for (int mt = 0; mt < 4; ++mt)
#pragma unroll
      for (int kt = 0; kt < 3; ++kt)
        a[mt][kt] = fragld(&qk[mt * 16 + l15][kt * 32 + quad * 8]);
    __syncthreads();   // all waves hold A-frags; q-writes may now clobber input
    const float qscale = 0.17677669529663687f;      // 1/sqrt(32)
    for (int nt = wv; nt < 18; nt += 4) {
      int n = nt * 16 + l15;
      bf8v bf[3];
#pragma unroll
      for (int kt = 0; kt < 3; ++kt)
        bf[kt] = fragld(qwb + n * CDIM + kt * 32 + quad * 8);
      if (nt < 12) {
        // q/k: transposed output -> lane holds C[n0+rg][m], b64 row-stores
        const int n0 = nt * 16 + quad * 4;
        f4v bias = *(const f4va*)&qb_f[n0];
        const bool isq = (nt < 6);
#pragma unroll
        for (int mt = 0; mt < 4; ++mt) {
          f4v c = {0.f, 0.f, 0.f, 0.f};
          c = mfma16(bf[0], a[mt][0], c);
          c = mfma16(bf[1], a[mt][1], c);
          c = mfma16(bf[2], a[mt][2], c);
          float v0 = c[0] + bias[0], v1 = c[1] + bias[1];
          float v2 = c[2] + bias[2], v3 = c[3] + bias[3];
          if (isq) { v0 *= qscale; v1 *= qscale; v2 *= qscale; v3 *= qscale; }
          u2v d; d[0] = pk2(v0, v1); d[1] = pk2(v2, v3);
          *(u2va*)&qk[mt * 16 + l15][n0] = d;
        }
      } else {
        // v: original orientation -> lane holds C[m0+rg][n], b64 into vt cols
        float bias = qb_f[n];
        const int hd = (n - 192) >> 5, dc = (n - 192) & 31;
#pragma unroll
        for (int mt = 0; mt < 4; ++mt) {
          f4v c = {0.f, 0.f, 0.f, 0.f};
          c = mfma16(a[mt][0], bf[0], c);
          c = mfma16(a[mt][1], bf[1], c);
          c = mfma16(a[mt][2], bf[2], c);
          u2v d; d[0] = pk2(c[0] + bias, c[1] + bias);
          d[1] = pk2(c[2] + bias, c[3] + bias);
          *(u2va*)&vt[hd][dc][mt * 16 + quad * 4] = d;
        }
      }
    }
  }
  __syncthreads();

  // ---- phase 4: attention per head; lane owns token-row m = wv*16+l15 --------
  {
    const int mrow = wv * 16 + l15;
    int mc = mrow > 48 ? 48 : mrow;
    const int ri = mc / 7, ci = mc - ri * 7;
    const int rcnt = reg3(whb * 7 + ri) * 3 + reg3(wwb * 7 + ci);
    // hoist h-invariant j-side quantities (j = jt*16 + quad*4 + rg)
    int ib_[4][4]; float ms_[4][4]; bool jv_[4][4];
#pragma unroll
    for (int jt = 0; jt < 4; ++jt)
#pragma unroll
      for (int rg = 0; rg < 4; ++rg) {
        int j = jt * 16 + quad * 4 + rg;
        jv_[jt][rg] = (j < NTOK);
        int jj = j > 48 ? 48 : j;
        int rj = jj / 7, cj = jj - rj * 7;
        int jcnt = reg3(whb * 7 + rj) * 3 + reg3(wwb * 7 + cj);
        ib_[jt][rg] = ((ri - rj + 6) * 13 + (ci - cj + 6)) * 3;
        ms_[jt][rg] = (jcnt != rcnt) ? -100.f : 0.f;
      }
#pragma unroll
    for (int h = 0; h < 3; ++h) {
      bf8v aq = fragld(&qk[wv * 16 + l15][h * 32 + quad * 8]);   // B operand (col=m)
      f4v S[4];
#pragma unroll
      for (int jt = 0; jt < 4; ++jt) {
        bf8v bk = fragld(&qk[jt * 16 + l15][96 + h * 32 + quad * 8]);  // A (row=j)
        f4v z = {0.f, 0.f, 0.f, 0.f};
        S[jt] = mfma16(bk, aq, z);     // S'[j][m]
      }
#pragma unroll
      for (int jt = 0; jt < 4; ++jt)
#pragma unroll
        for (int rg = 0; rg < 4; ++rg) {
          if (jv_[jt][rg]) S[jt][rg] += rel_f[ib_[jt][rg] + h] + ms_[jt][rg];
          else             S[jt][rg] = -1e30f;
        }
      // softmax over j for this lane's row m: in-reg tree + cross-quad (2 shfl)
      float mx0 = fmaxf(fmaxf(S[0][0], S[0][1]), fmaxf(S[0][2], S[0][3]));
      float mx1 = fmaxf(fmaxf(S[1][0], S[1][1]), fmaxf(S[1][2], S[1][3]));
      float mx2 = fmaxf(fmaxf(S[2][0], S[2][1]), fmaxf(S[2][2], S[2][3]));
      float mx3 = fmaxf(fmaxf(S[3][0], S[3][1]), fmaxf(S[3][2], S[3][3]));
      float mx = fmaxf(fmaxf(mx0, mx1), fmaxf(mx2, mx3));
      mx = fmaxf(mx, __shfl_xor(mx, 16, 64));
      mx = fmaxf(mx, __shfl_xor(mx, 32, 64));
      float s = 0.f;
#pragma unroll
      for (int jt = 0; jt < 4; ++jt) {
        float e0 = __expf(S[jt][0] - mx), e1 = __expf(S[jt][1] - mx);
        float e2 = __expf(S[jt][2] - mx), e3 = __expf(S[jt][3] - mx);
        S[jt][0] = e0; S[jt][1] = e1; S[jt][2] = e2; S[jt][3] = e3;
        s += (e0 + e1) + (e2 + e3);
      }
      s += __shfl_xor(s, 16, 64);
      s += __shfl_xor(s, 32, 64);
      float inv = 1.f / s;
#pragma unroll
      for (int jt = 0; jt < 4; ++jt) {
        u2v d; d[0] = pk2(S[jt][0] * inv, S[jt][1] * inv);
        d[1] = pk2(S[jt][2] * inv, S[jt][3] * inv);
        *(u2va*)&Pl[mrow][jt * 16 + quad * 4] = d;
      }
      bf8v ap0 = fragld(&Pl[wv * 16 + l15][quad * 8]);        // B operand (col=m)
      bf8v ap1 = fragld(&Pl[wv * 16 + l15][32 + quad * 8]);
#pragma unroll
      for (int dt = 0; dt < 2; ++dt) {
        bf8v bv0 = fragld(&vt[h][dt * 16 + l15][quad * 8]);   // A operand (row=d)
        bf8v bv1 = fragld(&vt[h][dt * 16 + l15][32 + quad * 8]);
        f4v c = {0.f, 0.f, 0.f, 0.f};
        c = mfma16(bv0, ap0, c);
        c = mfma16(bv1, ap1, c);     // C'[d][m]
        // att aliases q-region cols 32h..32h+31, own-wave rows only
        u2v d; d[0] = pk2(c[0], c[1]); d[1] = pk2(c[2], c[3]);
        *(u2va*)&qk[mrow][h * 32 + dt * 16 + quad * 4] = d;
      }
    }
  }
  __syncthreads();

  // ---- phase 5: proj GEMM (64x96)@(96x96) -> qk cols 0..95 (in-place) --------
  // static nt split (waves 0,1 do 2 tiles; 2,3 do 1) -- rule #20 safe
  {
    bf8v a[4][3];
#pragma unroll
    for (int mt = 0; mt < 4; ++mt)
#pragma unroll
      for (int kt = 0; kt < 3; ++kt)
        a[mt][kt] = fragld(&qk[mt * 16 + l15][kt * 32 + quad * 8]);
    __syncthreads();   // all waves hold att A-frags; out-writes may now clobber
    for (int nt = wv; nt < 6; nt += 4) {
      int n = nt * 16 + l15;
      bf8v bf[3];
#pragma unroll
      for (int kt = 0; kt < 3; ++kt)
        bf[kt] = fragld(pwb + n * CDIM + kt * 32 + quad * 8);
      const int n0 = nt * 16 + quad * 4;
      f4v bias = *(const f4va*)&pb_f[n0];
#pragma unroll
      for (int mt = 0; mt < 4; ++mt) {
        f4v c = {0.f, 0.f, 0.f, 0.f};
        c = mfma16(bf[0], a[mt][0], c);
        c = mfma16(bf[1], a[mt][1], c);
        c = mfma16(bf[2], a[mt][2], c);
        u2v d; d[0] = pk2(c[0] + bias[0], c[1] + bias[1]);
        d[1] = pk2(c[2] + bias[2], c[3] + bias[3]);
        *(u2va*)&qk[mt * 16 + l15][n0] = d;
      }
    }
  }
  __syncthreads();

  // ---- phase 6: contiguous coop store (in-place over this block's window) ----
  for (int idx = tid; idx < 588; idx += 256) {
    int row = idx / 12, cc = idx - row * 12;
    *(f4va*)(wbase + idx * 8) = *(const f4va*)&qk[row][cc * 8];
  }
}

// ---- K3: window-reverse + unshift + bf16->fp32 transpose. block=(b,h) --------
// sigma row-permutation of wtile kills the 7-way scalar-read bank conflicts:
// storage row sig(w) = (w>>2)|((w&3)<<4); store loop reads rows p4+16j (2-way).
__global__ __launch_bounds__(256, 8)
void swin_unpack(const u16* __restrict__ winbuf, float* __restrict__ out) {
  __shared__ __align__(16) u16 wtile[64][104];   // [sig(w)][c]
  const int bid = blockIdx.x;
  const int b = bid / FEAT_, h = bid - b * FEAT_;
  int hs = h - SHIFT_; if (hs < 0) hs += FEAT_;
  const int wrow = hs / 7, tr = hs - wrow * 7;
  const int tid = threadIdx.x, wv = tid >> 6, lane = tid & 63;

  for (int idx = tid; idx < 672; idx += 256) {
    int ww = idx / 84, r = idx - ww * 84;
    const u16* src = winbuf + ((size_t)((b * 64 + wrow * 8 + ww) * 49 + tr * 7)) * CDIM + r * 8;
    int wl = r / 12, cc = r - wl * 12;
    int ws = ww * 7 + wl;
    int w = ws + SHIFT_; if (w >= FEAT_) w -= FEAT_;
    int sr = (w >> 2) | ((w & 3) << 4);
    *(f4va*)&wtile[sr][cc * 8] = *(const f4va*)src;
  }
  __syncthreads();
  // vectorized float4 stores along w: 4 channel-groups x 14 lanes
  if (lane < 56) {
    const int g = lane / 14, p4 = lane - g * 14;
    float* obase = out + (size_t)b * CDIM * HWIM + h * FEAT_ + p4 * 4;
    for (int i = 0; i < 6; ++i) {
      int c = wv * 24 + i * 4 + g;
      f4v v;
#pragma unroll
      for (int j = 0; j < 4; ++j) v[j] = b2f(wtile[p4 + 16 * j][c]);  // sig(4p4+j)
      *(f4va*)(obase + (size_t)c * HWIM) = v;
    }
  }
}

// ---- fallback: round-2 monolithic kernel (used if ws too small) --------------
__global__ __launch_bounds__(256, 2)
void swin_fused_fb(const float* __restrict__ x,
                   const float* __restrict__ lng, const float* __restrict__ lnb,
                   const float* __restrict__ qw,  const float* __restrict__ qbv,
                   const float* __restrict__ pw,  const float* __restrict__ pbv,
                   const float* __restrict__ rel,
                   float* __restrict__ out) {
  __shared__ union { float xf[NTOK][97]; u16 qk[NPAD][200]; } A;
  __shared__ union { u16 win16[NPAD][104]; u16 outb[NPAD][98]; } Bu;
  __shared__ u16 vt[3][32][72];
  __shared__ u16 Pl[NPAD][72];
  __shared__ u16 att[NPAD][104];
  __shared__ float gw[CDIM], bwt[CDIM];
  __shared__ float rel_f[507];
  __shared__ float pb_f[CDIM];
  __shared__ float qb_f[3 * CDIM];

  const int blk = blockIdx.x;
  const int b = blk >> 6, wi = blk & 63;
  const int whb = wi >> 3, wwb = wi & 7;
  const int tid = threadIdx.x, wv = tid >> 6, lane = tid & 63;
  const int quad = lane >> 4, l15 = lane & 15;
  {
    int p = lane;
    if (p < NTOK) {
      int r = p / 7, cw = p - r * 7;
      int h = whb * 7 + r + SHIFT_;  if (h >= FEAT_) h -= FEAT_;
      int w = wwb * 7 + cw + SHIFT_; if (w >= FEAT_) w -= FEAT_;
      const float* xp = x + b * CDIM * HWIM + h * FEAT_ + w;
      for (int c = wv; c < CDIM; c += 4) A.xf[p][c] = xp[c * HWIM];
    }
    for (int i = tid; i < CDIM; i += 256) { gw[i] = lng[i]; bwt[i] = lnb[i]; pb_f[i] = pbv[i]; }
    for (int i = tid; i < 507; i += 256) rel_f[i] = rel[i];
    for (int i = tid; i < 3 * CDIM; i += 256) qb_f[i] = qbv[i];
  }
  __syncthreads();
  {
    int p = wv * 16 + (lane >> 2), cg = lane & 3;
    float s = 0.f, q = 0.f;
    if (p < NTOK)
      for (int i = 0; i < 24; ++i) { float v = A.xf[p][cg * 24 + i]; s += v; q += v * v; }
    s += __shfl_xor(s, 1, 64); s += __shfl_xor(s, 2, 64);
    q += __shfl_xor(q, 1, 64); q += __shfl_xor(q, 2, 64);
    float m = s * (1.f / 96.f);
    float r = rsqrtf(q * (1.f / 96.f) - m * m + 1e-5f);
    for (int i = 0; i < 24; ++i) {
      int c = cg * 24 + i;
      float v = (p < NTOK) ? (A.xf[p][c] - m) * r * gw[c] + bwt[c] : 0.f;
      Bu.win16[p][c] = f2b(v);
    }
  }
  __syncthreads();
  {
    bf8v a[4][3];
    for (int mt = 0; mt < 4; ++mt)
      for (int kt = 0; kt < 3; ++kt)
        a[mt][kt] = fragld(&Bu.win16[mt * 16 + l15][kt * 32 + quad * 8]);
    const float qscale = 0.17677669529663687f;
    for (int nt = wv; nt < 18; nt += 4) {
      int n = nt * 16 + l15;
      const float* wr = qw + n * CDIM;
      bf8v bf[3];
      for (int kt = 0; kt < 3; ++kt) bf[kt] = cvt8(wr + kt * 32 + quad * 8);
      float bias = qb_f[n];
      for (int mt = 0; mt < 4; ++mt) {
        f4v c = {0.f, 0.f, 0.f, 0.f};
        c = mfma16(a[mt][0], bf[0], c);
        c = mfma16(a[mt][1], bf[1], c);
        c = mfma16(a[mt][2], bf[2], c);
        for (int rg = 0; rg < 4; ++rg) {
          int m = mt * 16 + quad * 4 + rg;
          float v = c[rg] + bias;
          if (n < 96)        A.qk[m][n] = f2b(v * qscale);
          else if (n < 192)  A.qk[m][n] = f2b(v);
          else               vt[(n - 192) >> 5][(n - 192) & 31][m] = f2b(v);
        }
      }
    }
  }
  __syncthreads();
  {
    const int rbase = wv * 16 + quad * 4;
    int rcnt[4], ri_[4], ci_[4];
    for (int rg = 0; rg < 4; ++rg) {
      int r = rbase + rg; if (r > 48) r = 48;
      int ri = r / 7, ci = r - ri * 7;
      ri_[rg] = ri; ci_[rg] = ci;
      rcnt[rg] = reg3(whb * 7 + ri) * 3 + reg3(wwb * 7 + ci);
    }
    for (int h = 0; h < 3; ++h) {
      bf8v aq = fragld(&A.qk[wv * 16 + l15][h * 32 + quad * 8]);
      f4v S[4];
      for (int nt = 0; nt < 4; ++nt) {
        bf8v bk = fragld(&A.qk[nt * 16 + l15][96 + h * 32 + quad * 8]);
        f4v z = {0.f, 0.f, 0.f, 0.f};
        S[nt] = mfma16(aq, bk, z);
      }
      for (int nt = 0; nt < 4; ++nt) {
        int j = nt * 16 + l15;
        if (j < NTOK) {
          int rj = j / 7, cj = j - rj * 7;
          int jcnt = reg3(whb * 7 + rj) * 3 + reg3(wwb * 7 + cj);
          for (int rg = 0; rg < 4; ++rg) {
            float add = rel_f[((ri_[rg] - rj + 6) * 13 + (ci_[rg] - cj + 6)) * 3 + h];
            if (jcnt != rcnt[rg]) add -= 100.f;
            S[nt][rg] += add;
          }
        } else {
          for (int rg = 0; rg < 4; ++rg) S[nt][rg] = -1e30f;
        }
      }
      float inv[4];
      for (int rg = 0; rg < 4; ++rg) {
        float m = fmaxf(fmaxf(S[0][rg], S[1][rg]), fmaxf(S[2][rg], S[3][rg]));
        for (int off = 1; off < 16; off <<= 1) m = fmaxf(m, __shfl_xor(m, off, 64));
        float s = 0.f;
        for (int nt = 0; nt < 4; ++nt) { float e = __expf(S[nt][rg] - m); S[nt][rg] = e; s += e; }
        for (int off = 1; off < 16; off <<= 1) s += __shfl_xor(s, off, 64);
        inv[rg] = 1.f / s;
      }
      for (int nt = 0; nt < 4; ++nt) {
        int j = nt * 16 + l15;
        for (int rg = 0; rg < 4; ++rg) Pl[rbase + rg][j] = f2b(S[nt][rg] * inv[rg]);
      }
      bf8v ap0 = fragld(&Pl[wv * 16 + l15][quad * 8]);
      bf8v ap1 = fragld(&Pl[wv * 16 + l15][32 + quad * 8]);
      for (int nt = 0; nt < 2; ++nt) {
        bf8v bv0 = fragld(&vt[h][nt * 16 + l15][quad * 8]);
        bf8v bv1 = fragld(&vt[h][nt * 16 + l15][32 + quad * 8]);
        f4v c = {0.f, 0.f, 0.f, 0.f};
        c = mfma16(ap0, bv0, c);
        c = mfma16(ap1, bv1, c);
        for (int rg = 0; rg < 4; ++rg)
          att[rbase + rg][h * 32 + nt * 16 + l15] = f2b(c[rg]);
      }
    }
  }
  __syncthreads();
  {
    bf8v a[4][3];
    for (int mt = 0; mt < 4; ++mt)
      for (int kt = 0; kt < 3; ++kt)
        a[mt][kt] = fragld(&att[mt * 16 + l15][kt * 32 + quad * 8]);
    for (int nt = wv; nt < 6; nt += 4) {
      int n = nt * 16 + l15;
      const float* wr = pw + n * CDIM;
      bf8v bf[3];
      for (int kt = 0; kt < 3; ++kt) bf[kt] = cvt8(wr + kt * 32 + quad * 8);
      float bias = pb_f[n];
      for (int mt = 0; mt < 4; ++mt) {
        f4v c = {0.f, 0.f, 0.f, 0.f};
        c = mfma16(a[mt][0], bf[0], c);
        c = mfma16(a[mt][1], bf[1], c);
        c = mfma16(a[mt][2], bf[2], c);
        for (int rg = 0; rg < 4; ++rg)
          Bu.outb[mt * 16 + quad * 4 + rg][n] = f2b(c[rg] + bias);
      }
    }
  }
  __syncthreads();
  {
    int p = lane;
    if (p < NTOK) {
      int r = p / 7, cw = p - r * 7;
      int h = whb * 7 + r + SHIFT_;  if (h >= FEAT_) h -= FEAT_;
      int w = wwb * 7 + cw + SHIFT_; if (w >= FEAT_) w -= FEAT_;
      float* op = out + b * CDIM * HWIM + h * FEAT_ + w;
      for (int c = wv; c < CDIM; c += 4) op[c * HWIM] = b2f(Bu.outb[p][c]);
    }
  }
}

extern "C" void kernel_launch(void* const* d_in, const int* in_sizes, int n_in,
                              void* d_out, int out_size, void* d_ws, size_t ws_size,
                              hipStream_t stream) {
  (void)in_sizes; (void)n_in; (void)out_size;
  const float* x   = (const float*)d_in[0];
  const float* lng = (const float*)d_in[1];
  const float* lnb = (const float*)d_in[2];
  const float* qw  = (const float*)d_in[3];
  const float* qbv = (const float*)d_in[4];
  const float* pw  = (const float*)d_in[5];
  const float* pbv = (const float*)d_in[6];
  const float* rel = (const float*)d_in[7];
  float* out = (float*)d_out;

  if (ws_size >= WS_NEEDED) {
    u16* winbuf = (u16*)d_ws;
    u16* qwb = winbuf + WIN_ELEMS;
    u16* pwb = qwb + QW_ELEMS;
    swin_wcvt<<<dim3(144), dim3(256), 0, stream>>>(qw, pw, qwb, pwb);
    swin_ln_pack<<<dim3(128 * FEAT_), dim3(256), 0, stream>>>(x, lng, lnb, winbuf);
    swin_attn<<<dim3(8192), dim3(256), 0, stream>>>(winbuf, qwb, pwb, qbv, pbv, rel);
    swin_unpack<<<dim3(128 * FEAT_), dim3(256), 0, stream>>>(winbuf, out);
  } else {
    swin_fused_fb<<<dim3(8192), dim3(256), 0, stream>>>(x, lng, lnb, qw, qbv, pw, pbv, rel, out);
  }
}